// Round 1
// baseline (756.733 us; speedup 1.0000x reference)
//
#include <hip/hip_runtime.h>
#include <hip/hip_bf16.h>

#define T_LEN   8192
#define OBS     32
#define SDIM    5
#define NT      64          // transient table length (Riccati converged far before this)
#define LCHUNK  1024
#define NCHUNK  8           // T_LEN / LCHUNK
#define WARM    64          // z warm-up steps; rho(Mz)^64 ~ 1e-16
#define BATCH   256

#define COVS_OFF  10485760u   // 256*8192*5
#define LL_OFF    62914560u   // + 256*8192*25

#define WS_CSUM 0
#define WS_TBL  8             // per t: 50 floats (G[25], Mz[25])

__device__ __forceinline__ float readlane_f(float v, int l) {
  return __int_as_float(__builtin_amdgcn_readlane(__float_as_int(v), l));
}

// ---------------------------------------------------------------------------
// Kernel A: data-independent Riccati recursion, single wave, 5x5 element-per-lane.
// Produces per-t tables: G_t (= posterior cov = Kalman-gain core), Mz_t = (I - G_t B) A,
// plus C_SUM = sum_t of the ll constant, and zeroes the ll output region.
// ---------------------------------------------------------------------------
__global__ void riccati_kernel(const float* __restrict__ Am, const float* __restrict__ Cm,
                               const float* __restrict__ Qld, const float* __restrict__ Rld,
                               float* __restrict__ ws, float* __restrict__ llz)
{
  const int lane = threadIdx.x;
  for (int i = lane; i < BATCH; i += 64) llz[i] = 0.f;   // ll accumulators must start at 0

  const int r = (lane < 25) ? (lane / 5) : 0;
  const int c = (lane < 25) ? (lane % 5) : 0;

  float A[25], B[25];
  #pragma unroll
  for (int e = 0; e < 25; ++e) A[e] = Am[e];
  #pragma unroll
  for (int e = 0; e < 25; ++e) B[e] = 0.f;
  float sumR = 0.f;
  for (int o = 0; o < OBS; ++o) {
    const float rl = Rld[o];
    sumR += rl;
    const float rv = expf(-rl);
    float co[5];
    #pragma unroll
    for (int s = 0; s < 5; ++s) co[s] = Cm[o*5+s];
    #pragma unroll
    for (int e = 0; e < 25; ++e) B[e] += rv * co[e/5] * co[e%5];  // B = C^T R^-1 C
  }
  const float Qd = expf(Qld[r]);

  float P = (r == c) ? 1.f : 0.f;   // posterior covariance, element per lane
  double csum = 0.0;
  float clast = 0.f;
  const float LOG2PI = 1.8378770664093453f;

  for (int t = 0; t < NT; ++t) {
    // P_pred = A P A^T + Q
    float U = 0.f;
    #pragma unroll
    for (int k = 0; k < 5; ++k) U += A[r*5+k] * __shfl(P, 5*k+c);
    float Pp = (r == c) ? Qd : 0.f;
    #pragma unroll
    for (int k = 0; k < 5; ++k) Pp += __shfl(U, 5*r+k) * A[c*5+k];
    // M = I + B P_pred   (det M gives logdet S - logdet R; M^-1 gives G)
    float M = (r == c) ? 1.f : 0.f;
    #pragma unroll
    for (int k = 0; k < 5; ++k) M += B[r*5+k] * __shfl(Pp, 5*k+c);
    // Gauss-Jordan inverse of M with pivot-product determinant
    float N = (r == c) ? 1.f : 0.f;
    float logdet = 0.f;
    #pragma unroll
    for (int p = 0; p < 5; ++p) {
      const float piv  = __shfl(M, 6*p);
      const float invp = 1.f / piv;
      logdet += logf(piv);
      const float mp = __shfl(M, 5*p+c) * invp;
      const float np = __shfl(N, 5*p+c) * invp;
      const float f  = __shfl(M, 5*r+p);
      const bool isp = (r == p);
      M = isp ? mp : fmaf(-f, mp, M);
      N = isp ? np : fmaf(-f, np, N);
    }
    // G = P_pred M^-1  (= posterior covariance = P_new)
    float G = 0.f;
    #pragma unroll
    for (int k = 0; k < 5; ++k) G += __shfl(Pp, 5*r+k) * __shfl(N, 5*k+c);
    // Mz = (I - G B) A
    float W = 0.f;
    #pragma unroll
    for (int k = 0; k < 5; ++k) W += __shfl(G, 5*r+k) * B[k*5+c];
    float Mz = 0.f;
    #pragma unroll
    for (int k = 0; k < 5; ++k) {
      const float X = ((r == k) ? 1.f : 0.f) - __shfl(W, 5*r+k);
      Mz += X * A[k*5+c];
    }
    const float ct = -0.5f * (OBS * LOG2PI + sumR + logdet);
    csum += (double)ct;
    clast = ct;
    if (lane < 25) {
      ws[WS_TBL + t*50 + lane]      = G;
      ws[WS_TBL + t*50 + 25 + lane] = Mz;
    }
    P = G;
  }
  if (lane == 0) ws[WS_CSUM] = (float)(csum + (double)(T_LEN - NT) * (double)clast);
}

// ---------------------------------------------------------------------------
// Kernel B: per (batch, time-chunk) wave. 64 lanes compute u_t = C^T R^-1 y_t,
// q_t = y^T R^-1 y for 64 timesteps in parallel; replicated serial sweep
// z <- Mz z + G u (readlane-broadcast) produces states; ll via Woodbury quadform;
// covs are a broadcast of the G table.
// ---------------------------------------------------------------------------
__global__ __launch_bounds__(64, 2)
void filter_kernel(const float* __restrict__ y, const float* __restrict__ Am,
                   const float* __restrict__ Cm, const float* __restrict__ Rld,
                   float* __restrict__ out, const float* __restrict__ ws)
{
  const int lane = threadIdx.x;
  const int b  = blockIdx.x >> 3;
  const int ck = blockIdx.x & 7;

  __shared__ float sCw[OBS][SDIM];
  __shared__ float sRinv[OBS];
  __shared__ float sA[25];
  __shared__ float sB[25];
  __shared__ float sMz[NT][25];

  if (lane < OBS) {
    const float rv = expf(-Rld[lane]);
    sRinv[lane] = rv;
    #pragma unroll
    for (int s = 0; s < SDIM; ++s) sCw[lane][s] = Cm[lane*SDIM+s] * rv;
  }
  if (lane < 25) sA[lane] = Am[lane];
  __syncthreads();
  if (lane < 25) {
    const int i = lane / 5, j = lane % 5;
    float acc = 0.f;
    for (int o = 0; o < OBS; ++o) acc += sCw[o][i] * Cm[o*SDIM+j];
    sB[lane] = acc;
  }
  if (ck == 0) {
    for (int idx = lane; idx < NT*25; idx += 64)
      sMz[idx/25][idx%25] = ws[WS_TBL + (idx/25)*50 + 25 + (idx%25)];
  }
  __syncthreads();

  float Gss[25], Mzss[25];
  #pragma unroll
  for (int e = 0; e < 25; ++e) {
    Gss[e]  = ws[WS_TBL + (NT-1)*50 + e];
    Mzss[e] = ws[WS_TBL + (NT-1)*50 + 25 + e];
  }

  const int t0 = ck * LCHUNK;
  const int tstart = (ck == 0) ? 0 : (t0 - WARM);
  const int ngroups = (t0 + LCHUNK - tstart) >> 6;

  const float* yb = y + (size_t)b * T_LEN * OBS;
  float* st = out + (size_t)b * T_LEN * SDIM;
  float* cv = out + (size_t)COVS_OFF + (size_t)b * T_LEN * 25;

  float z[5] = {0,0,0,0,0};
  float llacc = 0.f;

  float4 yv[8], yvn[8];
  {
    const float4* yr = (const float4*)(yb + (size_t)(tstart + lane) * OBS);
    #pragma unroll
    for (int i2 = 0; i2 < 8; ++i2) yv[i2] = yr[i2];
  }

  for (int g = 0; g < ngroups; ++g) {
    const int tb = tstart + (g << 6);
    const int t  = tb + lane;
    const bool post  = (t >= t0);       // false only in warm-up group
    const bool trans = (tb < NT);       // only ck==0, g==0

    // prefetch next group's y rows (double-buffer in regs)
    {
      const int tn = (g + 1 < ngroups) ? (tb + 64 + lane) : t;
      const float4* yr = (const float4*)(yb + (size_t)tn * OBS);
      #pragma unroll
      for (int i2 = 0; i2 < 8; ++i2) yvn[i2] = yr[i2];
    }

    // u = C^T R^-1 y_t ; qw = y^T R^-1 y  (lane-parallel over 64 t's)
    float u[5] = {0,0,0,0,0};
    float qw = 0.f;
    #pragma unroll
    for (int i2 = 0; i2 < 8; ++i2) {
      const float vals[4] = {yv[i2].x, yv[i2].y, yv[i2].z, yv[i2].w};
      #pragma unroll
      for (int k = 0; k < 4; ++k) {
        const int o = i2*4 + k;
        const float f = vals[k];
        qw = fmaf(sRinv[o]*f, f, qw);
        #pragma unroll
        for (int s = 0; s < 5; ++s) u[s] = fmaf(sCw[o][s], f, u[s]);
      }
    }

    // bvec = G_t u  (per-lane)
    float bvec[5];
    if (trans) {
      const float* Gt = ws + WS_TBL + t*50;
      #pragma unroll
      for (int s = 0; s < 5; ++s) {
        float acc = 0.f;
        #pragma unroll
        for (int k = 0; k < 5; ++k) acc = fmaf(Gt[s*5+k], u[k], acc);
        bvec[s] = acc;
      }
    } else {
      #pragma unroll
      for (int s = 0; s < 5; ++s) {
        float acc = 0.f;
        #pragma unroll
        for (int k = 0; k < 5; ++k) acc = fmaf(Gss[s*5+k], u[k], acc);
        bvec[s] = acc;
      }
    }

    // serial sweep over 64 steps, replicated on all lanes; lane j snapshots its step
    float zprev[5] = {0,0,0,0,0}, znew[5] = {0,0,0,0,0};
    if (!trans) {
      #pragma unroll 8
      for (int j = 0; j < 64; ++j) {
        float nz[5];
        #pragma unroll
        for (int s = 0; s < 5; ++s) {
          float acc = readlane_f(bvec[s], j);
          #pragma unroll
          for (int k = 0; k < 5; ++k) acc = fmaf(Mzss[s*5+k], z[k], acc);
          nz[s] = acc;
        }
        const bool mine = (lane == j);
        #pragma unroll
        for (int s = 0; s < 5; ++s) {
          zprev[s] = mine ? z[s]  : zprev[s];
          znew[s]  = mine ? nz[s] : znew[s];
          z[s] = nz[s];
        }
      }
    } else {
      #pragma unroll 1
      for (int j = 0; j < 64; ++j) {
        float nz[5];
        #pragma unroll
        for (int s = 0; s < 5; ++s) {
          float acc = readlane_f(bvec[s], j);
          #pragma unroll
          for (int k = 0; k < 5; ++k) acc = fmaf(sMz[j][s*5+k], z[k], acc);
          nz[s] = acc;
        }
        const bool mine = (lane == j);
        #pragma unroll
        for (int s = 0; s < 5; ++s) {
          zprev[s] = mine ? z[s]  : zprev[s];
          znew[s]  = mine ? nz[s] : znew[s];
          z[s] = nz[s];
        }
      }
    }

    if (post) {
      // z_pred = A z_{t-1}
      float zp[5];
      #pragma unroll
      for (int s = 0; s < 5; ++s) {
        float acc = 0.f;
        #pragma unroll
        for (int k = 0; k < 5; ++k) acc = fmaf(sA[s*5+k], zprev[k], acc);
        zp[s] = acc;
      }
      // w = u - B z_pred ; vRv = qw - 2 u.zp + zp.B zp
      float w[5], zBz = 0.f, uzp = 0.f;
      #pragma unroll
      for (int s = 0; s < 5; ++s) {
        float bz = 0.f;
        #pragma unroll
        for (int k = 0; k < 5; ++k) bz = fmaf(sB[s*5+k], zp[k], bz);
        w[s] = u[s] - bz;
        zBz = fmaf(zp[s], bz, zBz);
        uzp = fmaf(u[s], zp[s], uzp);
      }
      const float vRv = qw - 2.f*uzp + zBz;
      float wGw = 0.f;
      if (t < NT) {
        const float* Gt = ws + WS_TBL + t*50;
        #pragma unroll
        for (int i2 = 0; i2 < 5; ++i2) {
          #pragma unroll
          for (int k = 0; k < 5; ++k) wGw = fmaf(Gt[i2*5+k]*w[i2], w[k], wGw);
        }
        #pragma unroll
        for (int e = 0; e < 25; ++e) cv[(size_t)t*25 + e] = Gt[e];
      } else {
        #pragma unroll
        for (int i2 = 0; i2 < 5; ++i2) {
          #pragma unroll
          for (int k = 0; k < 5; ++k) wGw = fmaf(Gss[i2*5+k]*w[i2], w[k], wGw);
        }
        #pragma unroll
        for (int e = 0; e < 25; ++e) cv[(size_t)t*25 + e] = Gss[e];
      }
      llacc += (vRv - wGw);
      #pragma unroll
      for (int s = 0; s < 5; ++s) st[(size_t)t*5 + s] = znew[s];
    }

    #pragma unroll
    for (int i2 = 0; i2 < 8; ++i2) yv[i2] = yvn[i2];
  }

  // reduce quadform sum across lanes, one atomic per block
  #pragma unroll
  for (int off = 32; off >= 1; off >>= 1) llacc += __shfl_down(llacc, off);
  if (lane == 0) {
    float v = -0.5f * llacc;
    if (ck == 0) v += ws[WS_CSUM];   // sum of per-step ll constants
    atomicAdd(out + (size_t)LL_OFF + b, v);
  }
}

extern "C" void kernel_launch(void* const* d_in, const int* in_sizes, int n_in,
                              void* d_out, int out_size, void* d_ws, size_t ws_size,
                              hipStream_t stream) {
  const float* y   = (const float*)d_in[0];
  const float* A   = (const float*)d_in[1];
  const float* C   = (const float*)d_in[2];
  const float* Qld = (const float*)d_in[3];
  const float* Rld = (const float*)d_in[4];
  float* out = (float*)d_out;
  float* ws  = (float*)d_ws;

  riccati_kernel<<<1, 64, 0, stream>>>(A, C, Qld, Rld, ws, out + (size_t)LL_OFF);
  filter_kernel<<<BATCH*NCHUNK, 64, 0, stream>>>(y, A, C, Rld, out, ws);
}